// Round 9
// baseline (3652.666 us; speedup 1.0000x reference)
//
#include <hip/hip_runtime.h>
#include <math.h>

#define N_NODES  200000
#define N_EDGES  1600000
#define N_GRAPHS 10000
#define IN_F     74
#define HID      128
#define DEPTH    3

#define NBUCK 391          // ceil(N_NODES / 512): bucket = id >> 9
#define G1    512          // blocks in count/scatter pass
#define CHUNK 3125         // N_EDGES / G1 (exact)
#define NTOT  (NBUCK * G1) // 200192 scan elements

typedef __attribute__((ext_vector_type(8))) short short8;
typedef __attribute__((ext_vector_type(8))) unsigned short ushort8v;
typedef __attribute__((ext_vector_type(4))) float floatx4;

__device__ __forceinline__ float silu_f(float x) {
    return x / (1.0f + __expf(-x));
}

__device__ __forceinline__ unsigned short f2bf(float f) {
    union { float f; unsigned int u; } v; v.f = f;
    unsigned int r = (v.u + 0x7fff + ((v.u >> 16) & 1)) >> 16;   // RNE
    return (unsigned short)r;
}

__device__ __forceinline__ float bf2f(unsigned short u) {
    union { unsigned int u; float f; } v; v.u = ((unsigned int)u) << 16;
    return v.f;
}

// ================= atomic-free CSR build (radix partition by id>>9) =================

__global__ void count_kernel(const int* __restrict__ src, const int* __restrict__ dst,
                             int* __restrict__ cnt_d, int* __restrict__ cnt_s) {
    __shared__ int hd[NBUCK], hs[NBUCK];
    int t = threadIdx.x, b = blockIdx.x;
    for (int i = t; i < NBUCK; i += 256) { hd[i] = 0; hs[i] = 0; }
    __syncthreads();
    int e0 = b * CHUNK;
    for (int i = t; i < CHUNK; i += 256) {
        int e = e0 + i;
        atomicAdd(&hd[dst[e] >> 9], 1);
        atomicAdd(&hs[src[e] >> 9], 1);
    }
    __syncthreads();
    for (int i = t; i < NBUCK; i += 256) {
        cnt_d[i * G1 + b] = hd[i];
        cnt_s[i * G1 + b] = hs[i];
    }
}

__global__ void gscan1(const int* __restrict__ in, int* __restrict__ out,
                       int* __restrict__ bsums, int n) {
    __shared__ int a[256], b2[256];
    int t = threadIdx.x;
    int i = blockIdx.x * 256 + t;
    a[t] = (i < n) ? in[i] : 0;
    __syncthreads();
    int* s = a; int* d = b2;
    #pragma unroll
    for (int off = 1; off < 256; off <<= 1) {
        int v = s[t];
        if (t >= off) v += s[t - off];
        d[t] = v;
        __syncthreads();
        int* tmp = s; s = d; d = tmp;
    }
    if (i < n) out[i] = (t ? s[t - 1] : 0);
    if (t == 255) bsums[blockIdx.x] = s[255];
}

__global__ void gscan2(int* __restrict__ bsums, int nb) {
    __shared__ int a[1024], b[1024];
    int t = threadIdx.x;
    a[t] = (t < nb) ? bsums[t] : 0;
    __syncthreads();
    int* s = a; int* d = b;
    for (int off = 1; off < 1024; off <<= 1) {
        int v = s[t];
        if (t >= off) v += s[t - off];
        d[t] = v;
        __syncthreads();
        int* tmp = s; s = d; d = tmp;
    }
    if (t < nb) bsums[t] = s[t];
}

__global__ void gscan3(int* __restrict__ out, const int* __restrict__ bsums, int n) {
    int i = blockIdx.x * 256 + threadIdx.x;
    if (i < n && blockIdx.x > 0) out[i] += bsums[blockIdx.x - 1];
}

__global__ void scatter_kernel(const int* __restrict__ src, const int* __restrict__ dst,
                               const int* __restrict__ offs_d, const int* __restrict__ offs_s,
                               int2* __restrict__ ebuf, int* __restrict__ sbuf) {
    __shared__ int cd[NBUCK], cs[NBUCK];
    int t = threadIdx.x, b = blockIdx.x;
    for (int i = t; i < NBUCK; i += 256) {
        cd[i] = offs_d[i * G1 + b];
        cs[i] = offs_s[i * G1 + b];
    }
    __syncthreads();
    int e0 = b * CHUNK;
    for (int i = t; i < CHUNK; i += 256) {
        int e = e0 + i;
        int d = dst[e], s = src[e];
        int pd = atomicAdd(&cd[d >> 9], 1);
        int2 p; p.x = d; p.y = s;
        ebuf[pd] = p;
        int ps = atomicAdd(&cs[s >> 9], 1);
        sbuf[ps] = s;
    }
}

// esrc is PACKED: src (18 bits) | dst_local_to_64_block (6 bits) << 18
__global__ __launch_bounds__(512)
void csr_kernel(const int2* __restrict__ ebuf, const int* __restrict__ offs_d,
                int* __restrict__ row_off, int* __restrict__ esrc,
                float* __restrict__ norm_dst) {
    __shared__ int deg[512];
    __shared__ int sa[512], sb[512];
    int k = blockIdx.x, t = threadIdx.x;
    int base = k << 9;
    int estart = offs_d[k * G1];
    int eend = (k + 1 < NBUCK) ? offs_d[(k + 1) * G1] : N_EDGES;
    deg[t] = 0;
    __syncthreads();
    for (int e = estart + t; e < eend; e += 512)
        atomicAdd(&deg[ebuf[e].x - base], 1);
    __syncthreads();
    sa[t] = deg[t];
    __syncthreads();
    int* ps = sa; int* pd = sb;
    #pragma unroll
    for (int off = 1; off < 512; off <<= 1) {
        int v = ps[t];
        if (t >= off) v += ps[t - off];
        pd[t] = v;
        __syncthreads();
        int* tmp = ps; ps = pd; pd = tmp;
    }
    int excl = t ? ps[t - 1] : 0;
    int n = base + t;
    if (n <= N_NODES) row_off[n] = estart + excl;
    if (n < N_NODES)  norm_dst[n] = rsqrtf(fmaxf((float)deg[t], 1.0f));
    __syncthreads();
    pd[t] = estart + excl;
    __syncthreads();
    for (int e = estart + t; e < eend; e += 512) {
        int2 ed = ebuf[e];
        int pos = atomicAdd(&pd[ed.x - base], 1);
        esrc[pos] = ed.y | ((ed.x & 63) << 18);
    }
}

__global__ __launch_bounds__(512)
void degsrc_kernel(const int* __restrict__ sbuf, const int* __restrict__ offs_s,
                   float* __restrict__ norm_src) {
    __shared__ int deg[512];
    int k = blockIdx.x, t = threadIdx.x;
    int base = k << 9;
    int estart = offs_s[k * G1];
    int eend = (k + 1 < NBUCK) ? offs_s[(k + 1) * G1] : N_EDGES;
    deg[t] = 0;
    __syncthreads();
    for (int e = estart + t; e < eend; e += 512)
        atomicAdd(&deg[sbuf[e] - base], 1);
    __syncthreads();
    int n = base + t;
    if (n < N_NODES) norm_src[n] = rsqrtf(fmaxf((float)deg[t], 1.0f));
}

// ================= weight prep =================
__global__ void wprep_kernel(const float* __restrict__ w_in, const float* __restrict__ gw,
                             const float* __restrict__ w_out,
                             unsigned short* __restrict__ wtin,   // [128][96]
                             unsigned short* __restrict__ wtg,    // [3][128][128]
                             unsigned short* __restrict__ wtout)  // [128][128]
{
    int i = blockIdx.x * 256 + threadIdx.x;
    if (i < 128 * 96) {
        int n = i / 96, k = i - n * 96;
        wtin[i] = (k < IN_F) ? f2bf(w_in[k * 128 + n]) : (unsigned short)0;
    } else if (i < 128 * 96 + 3 * 128 * 128) {
        int j = i - 128 * 96;
        int layer = j / 16384, r = j - layer * 16384;
        int n = r >> 7, k = r & 127;
        wtg[j] = f2bf(gw[((size_t)layer * 128 + k) * 128 + n]);
    } else if (i < 128 * 96 + 3 * 128 * 128 + 128 * 128) {
        int j = i - (128 * 96 + 3 * 128 * 128);
        int n = j >> 7, k = j & 127;
        wtout[j] = f2bf(w_out[k * 128 + n]);
    }
}

// ================= fused conv: edge-parallel gather -> MFMA -> silu [-> MFMA2 -> silu] =================
// Block: 256 threads, 64 dst nodes (N_NODES % 64 == 0).
// Gather: LDS f32 accumulator (swizzled p(col)=16q+c), ds_add_f32 atomics,
// 16 threads/edge (coalesced 256B row reads), per-edge q-rotation to dodge
// same-word / same-bank collisions of same-dst adjacent edges.
// MFMA tiles in conflict-free fragment layout: A[(kchunk*64+m)*8+q], B[(kchunk*128+n)*8+q].
template<bool SCALE_NORM, bool SECOND>
__launch_bounds__(256)
__global__ void fused_conv(const unsigned short* __restrict__ h,
                           const int* __restrict__ esrc, const int* __restrict__ row_off,
                           const float* __restrict__ norm_dst,
                           const unsigned short* __restrict__ WT,   // [128][128]
                           const float* __restrict__ bias, const float* __restrict__ norm_src,
                           const unsigned short* __restrict__ WT2,  // [128][128] (SECOND)
                           const float* __restrict__ bias2,
                           unsigned short* __restrict__ out) {
    __shared__ unsigned short lds_af[64 * 128];   // 16 KB: A fragments / final C repack
    __shared__ float accU[64 * 128];              // 32 KB: f32 gather acc, then B fragments
    unsigned short* lds_bf = (unsigned short*)accU;

    const int t = threadIdx.x;
    const int rowbase = blockIdx.x * 64;

    // ---- zero acc ----
    float4* accz = (float4*)accU;
    #pragma unroll
    for (int k = 0; k < 8; ++k)
        accz[k * 256 + t] = (float4){0.f, 0.f, 0.f, 0.f};
    __syncthreads();

    // ---- edge-parallel gather ----
    const int c = t & 15;
    const int beg = row_off[rowbase];
    const int end = row_off[rowbase + 64];
    for (int e = beg + (t >> 4); e < end; e += 16) {
        int p = esrc[e];
        int s = p & 0x3FFFF;
        int dl = (p >> 18) & 63;
        ushort8v v = *(const ushort8v*)(h + (size_t)s * HID + c * 8);
        float* arow = accU + dl * 128 + c;
        #pragma unroll
        for (int i = 0; i < 8; ++i) {
            int q = (i + e) & 7;                    // rotated issue order
            atomicAdd(arow + 16 * q, bf2f(v[q]));   // ds_add_f32, word = dl*128 + 16q + c
        }
    }

    // ---- B1 -> registers (issues overlap the tail of other waves' gathers) ----
    ushort8v breg[8];
    #pragma unroll
    for (int k = 0; k < 8; ++k) {
        int j = k * 256 + t;                 // 2048 chunk tasks: n = j>>4, kc = j&15
        breg[k] = *(const ushort8v*)(WT + (j >> 4) * 128 + (j & 15) * 8);
    }
    __syncthreads();

    // ---- readout: acc -> *norm_dst -> bf16 A-frags ----
    #pragma unroll
    for (int k = 0; k < 4; ++k) {
        int j = k * 256 + t;                 // 1024 tasks: row = j>>4, chunk cc = j&15
        int row = j >> 4, cc = j & 15;
        float nd = norm_dst[rowbase + row];
        ushort8v o;
        #pragma unroll
        for (int q = 0; q < 8; ++q)
            o[q] = f2bf(accU[row * 128 + 16 * q + cc] * nd);
        *(ushort8v*)&lds_af[(cc * 64 + row) * 8] = o;
    }
    __syncthreads();

    // ---- B1 regs -> LDS fragments (reuses acc space) ----
    #pragma unroll
    for (int k = 0; k < 8; ++k) {
        int j = k * 256 + t;
        *(ushort8v*)&lds_bf[((j & 15) * 128 + (j >> 4)) * 8] = breg[k];
    }
    __syncthreads();

    const int lane = t & 63;
    const int w  = t >> 6;
    const int wr = w & 1;
    const int wc = w >> 1;
    const int l15 = lane & 15, quad = lane >> 4;

    floatx4 acc[4][2];
    #pragma unroll
    for (int tn = 0; tn < 4; ++tn)
        #pragma unroll
        for (int rt = 0; rt < 2; ++rt)
            acc[tn][rt] = (floatx4){0.f, 0.f, 0.f, 0.f};

    // ---- K-loop 1 (conflict-free fragment reads) ----
    #pragma unroll
    for (int ks = 0; ks < 4; ++ks) {
        int kc = ks * 4 + quad;
        short8 bk[4];
        #pragma unroll
        for (int tn = 0; tn < 4; ++tn)
            bk[tn] = *(const short8*)&lds_bf[(kc * 128 + wc * 64 + tn * 16 + l15) * 8];
        short8 af[2];
        #pragma unroll
        for (int rt = 0; rt < 2; ++rt)
            af[rt] = *(const short8*)&lds_af[(kc * 64 + wr * 32 + rt * 16 + l15) * 8];
        #pragma unroll
        for (int tn = 0; tn < 4; ++tn)
            #pragma unroll
            for (int rt = 0; rt < 2; ++rt)
                acc[tn][rt] = __builtin_amdgcn_mfma_f32_16x16x32_bf16(
                    af[rt], bk[tn], acc[tn][rt], 0, 0, 0);
    }

    __syncthreads();   // everyone done reading lds_af / lds_bf

    if constexpr (SECOND) {
        // ---- epilogue 1 -> A2 fragments; B2 global -> LDS ----
        #pragma unroll
        for (int tn = 0; tn < 4; ++tn) {
            int col = wc * 64 + tn * 16 + l15;
            float b = bias[col];
            int c2 = col >> 3, q2 = col & 7;
            #pragma unroll
            for (int rt = 0; rt < 2; ++rt) {
                #pragma unroll
                for (int r = 0; r < 4; ++r) {
                    int row = wr * 32 + rt * 16 + quad * 4 + r;
                    float v = silu_f(acc[tn][rt][r] + b);
                    if (SCALE_NORM) v *= norm_src[rowbase + row];
                    lds_af[(c2 * 64 + row) * 8 + q2] = f2bf(v);
                }
            }
        }
        #pragma unroll
        for (int k = 0; k < 8; ++k) {
            int j = k * 256 + t;
            *(ushort8v*)&lds_bf[((j & 15) * 128 + (j >> 4)) * 8] =
                *(const ushort8v*)(WT2 + (j >> 4) * 128 + (j & 15) * 8);
        }
        #pragma unroll
        for (int tn = 0; tn < 4; ++tn)
            #pragma unroll
            for (int rt = 0; rt < 2; ++rt)
                acc[tn][rt] = (floatx4){0.f, 0.f, 0.f, 0.f};
        __syncthreads();

        // ---- K-loop 2 ----
        #pragma unroll
        for (int ks = 0; ks < 4; ++ks) {
            int kc = ks * 4 + quad;
            short8 bk[4];
            #pragma unroll
            for (int tn = 0; tn < 4; ++tn)
                bk[tn] = *(const short8*)&lds_bf[(kc * 128 + wc * 64 + tn * 16 + l15) * 8];
            short8 af[2];
            #pragma unroll
            for (int rt = 0; rt < 2; ++rt)
                af[rt] = *(const short8*)&lds_af[(kc * 64 + wr * 32 + rt * 16 + l15) * 8];
            #pragma unroll
            for (int tn = 0; tn < 4; ++tn)
                #pragma unroll
                for (int rt = 0; rt < 2; ++rt)
                    acc[tn][rt] = __builtin_amdgcn_mfma_f32_16x16x32_bf16(
                        af[rt], bk[tn], acc[tn][rt], 0, 0, 0);
        }
        __syncthreads();

        // ---- epilogue 2 -> row-major lds_af ----
        #pragma unroll
        for (int tn = 0; tn < 4; ++tn) {
            int col = wc * 64 + tn * 16 + l15;
            float b = bias2[col];
            #pragma unroll
            for (int rt = 0; rt < 2; ++rt) {
                #pragma unroll
                for (int r = 0; r < 4; ++r) {
                    int row = wr * 32 + rt * 16 + quad * 4 + r;
                    lds_af[row * 128 + col] = f2bf(silu_f(acc[tn][rt][r] + b));
                }
            }
        }
    } else {
        // ---- epilogue -> row-major lds_af ----
        #pragma unroll
        for (int tn = 0; tn < 4; ++tn) {
            int col = wc * 64 + tn * 16 + l15;
            float b = bias[col];
            #pragma unroll
            for (int rt = 0; rt < 2; ++rt) {
                #pragma unroll
                for (int r = 0; r < 4; ++r) {
                    int row = wr * 32 + rt * 16 + quad * 4 + r;
                    float v = silu_f(acc[tn][rt][r] + b);
                    if (SCALE_NORM) v *= norm_src[rowbase + row];
                    lds_af[row * 128 + col] = f2bf(v);
                }
            }
        }
    }

    __syncthreads();
    // ---- coalesced bf16 store ----
    #pragma unroll
    for (int j = 0; j < 4; ++j) {
        int e = j * 256 + t;
        int r = e >> 4;
        int cc = (e & 15) * 8;
        *(ushort8v*)(out + (size_t)(rowbase + r) * 128 + cc) = *(const ushort8v*)&lds_af[r * 128 + cc];
    }
}

// ================= input projection: fp32 x [N][74] @ wtin -> silu * norm_src -> bf16 =================
__launch_bounds__(256)
__global__ void inproj_gemm(const float* __restrict__ in, const unsigned short* __restrict__ WT,
                            const float* __restrict__ bias, const float* __restrict__ norm_src,
                            unsigned short* __restrict__ out) {
    constexpr int KP = 96, ASTR = 136, BSTR = 104;
    __shared__ unsigned short lds_a[64 * ASTR];
    __shared__ unsigned short lds_b[128 * BSTR];
    const int t = threadIdx.x;
    const int rowbase = blockIdx.x * 64;

    #pragma unroll
    for (int j = 0; j < 6; ++j) {
        int slot = j * 256 + t;
        int n = slot / 12, k = (slot - n * 12) * 8;
        *(ushort8v*)&lds_b[n * BSTR + k] = *(const ushort8v*)(WT + n * KP + k);
    }

    for (int i = t; i < 64 * 37; i += 256) {
        int r = i / 37, kk = (i - r * 37) * 2;
        float2 v = *(const float2*)(in + (size_t)(rowbase + r) * IN_F + kk);
        lds_a[r * ASTR + kk]     = f2bf(v.x);
        lds_a[r * ASTR + kk + 1] = f2bf(v.y);
    }
    for (int i = t; i < 64 * 22; i += 256) {
        int r = i / 22, kk = 74 + (i - r * 22);
        lds_a[r * ASTR + kk] = 0;
    }

    const int lane = t & 63;
    const int w  = t >> 6;
    const int wr = w & 1;
    const int wc = w >> 1;
    const int l15 = lane & 15, quad = lane >> 4;

    floatx4 acc[4][2];
    #pragma unroll
    for (int tn = 0; tn < 4; ++tn)
        #pragma unroll
        for (int rt = 0; rt < 2; ++rt)
            acc[tn][rt] = (floatx4){0.f, 0.f, 0.f, 0.f};

    __syncthreads();

    #pragma unroll
    for (int ks = 0; ks < 3; ++ks) {
        short8 bk[4];
        #pragma unroll
        for (int tn = 0; tn < 4; ++tn)
            bk[tn] = *(const short8*)&lds_b[(wc * 64 + tn * 16 + l15) * BSTR + ks * 32 + quad * 8];
        short8 af[2];
        #pragma unroll
        for (int rt = 0; rt < 2; ++rt)
            af[rt] = *(const short8*)&lds_a[(wr * 32 + rt * 16 + l15) * ASTR + ks * 32 + quad * 8];
        #pragma unroll
        for (int tn = 0; tn < 4; ++tn)
            #pragma unroll
            for (int rt = 0; rt < 2; ++rt)
                acc[tn][rt] = __builtin_amdgcn_mfma_f32_16x16x32_bf16(
                    af[rt], bk[tn], acc[tn][rt], 0, 0, 0);
    }

    __syncthreads();
    #pragma unroll
    for (int tn = 0; tn < 4; ++tn) {
        int col = wc * 64 + tn * 16 + l15;
        float b = bias[col];
        #pragma unroll
        for (int rt = 0; rt < 2; ++rt) {
            #pragma unroll
            for (int r = 0; r < 4; ++r) {
                int row = wr * 32 + rt * 16 + quad * 4 + r;
                float v = silu_f(acc[tn][rt][r] + b) * norm_src[rowbase + row];
                lds_a[row * ASTR + col] = f2bf(v);
            }
        }
    }
    __syncthreads();
    #pragma unroll
    for (int j = 0; j < 4; ++j) {
        int e = j * 256 + t;
        int r = e >> 4;
        int c = (e & 15) * 8;
        *(ushort8v*)(out + (size_t)(rowbase + r) * 128 + c) = *(const ushort8v*)&lds_a[r * ASTR + c];
    }
}

// ================= fp32 GEMM (small final matmul) =================
template<int K, bool DO_SILU>
__launch_bounds__(256)
__global__ void gemm_kernel(const float* __restrict__ in, const float* __restrict__ W,
                            const float* __restrict__ bias, float* __restrict__ out, int nrows) {
    __shared__ float wl[64 * HID];
    __shared__ float xl[32 * K];
    int t = threadIdx.x;
    int row0 = blockIdx.x * 32;

    for (int i = t; i < 32 * K; i += 256) {
        int r = i / K, k = i - r * K;
        int gr = row0 + r;
        xl[i] = (gr < nrows) ? in[(size_t)gr * K + k] : 0.0f;
    }

    int col = t & (HID - 1);
    int rg  = t >> 7;
    float acc[16];
    #pragma unroll
    for (int rr = 0; rr < 16; ++rr) acc[rr] = 0.0f;

    for (int c = 0; c < K; c += 64) {
        int kc = (K - c < 64) ? (K - c) : 64;
        __syncthreads();
        for (int i = t; i < kc * HID; i += 256) wl[i] = W[(size_t)c * HID + i];
        __syncthreads();
        for (int kk = 0; kk < kc; ++kk) {
            float w = wl[kk * HID + col];
            int k = c + kk;
            #pragma unroll
            for (int rr = 0; rr < 16; ++rr)
                acc[rr] += xl[(rg * 16 + rr) * K + k] * w;
        }
    }

    float b = bias[col];
    #pragma unroll
    for (int rr = 0; rr < 16; ++rr) {
        int r = row0 + rg * 16 + rr;
        if (r < nrows) {
            float v = acc[rr] + b;
            if (DO_SILU) v = silu_f(v);
            out[(size_t)r * HID + col] = v;
        }
    }
}

// ================= pooling: sorted graph_ids -> segmented sum =================
__device__ __forceinline__ int lower_bound_gid(const int* __restrict__ gid, int val) {
    int lo = 0, hi = N_NODES;
    while (lo < hi) {
        int mid = (lo + hi) >> 1;
        if (gid[mid] < val) lo = mid + 1; else hi = mid;
    }
    return lo;
}

__global__ void pool_kernel(const unsigned short* __restrict__ h, const int* __restrict__ gid,
                            float* __restrict__ pooled) {
    int g = blockIdx.x * 4 + (threadIdx.x >> 6);
    int lane = threadIdx.x & 63;
    int beg = lower_bound_gid(gid, g);
    int end = lower_bound_gid(gid, g + 1);
    float s0 = 0.0f, s1 = 0.0f;
    const unsigned int* hp = (const unsigned int*)h;
    for (int n = beg; n < end; ++n) {
        unsigned int u = hp[(size_t)n * 64 + lane];
        s0 += bf2f((unsigned short)(u & 0xffff));
        s1 += bf2f((unsigned short)(u >> 16));
    }
    float2 o; o.x = s0; o.y = s1;
    *(float2*)(pooled + (size_t)g * HID + lane * 2) = o;
}

extern "C" void kernel_launch(void* const* d_in, const int* in_sizes, int n_in,
                              void* d_out, int out_size, void* d_ws, size_t ws_size,
                              hipStream_t stream) {
    const float* x     = (const float*)d_in[0];
    const int*   src   = (const int*)  d_in[1];
    const int*   dst   = (const int*)  d_in[2];
    const int*   gid   = (const int*)  d_in[3];
    const float* w_in  = (const float*)d_in[4];
    const float* b_in  = (const float*)d_in[5];
    const float* gw    = (const float*)d_in[6];
    const float* gb    = (const float*)d_in[7];
    const float* w_out = (const float*)d_in[8];
    const float* b_out = (const float*)d_in[9];
    const float* w_ff  = (const float*)d_in[10];
    const float* b_ff  = (const float*)d_in[11];
    float* out = (float*)d_out;

    char* w = (char*)d_ws;
    size_t off = 0;
    auto alloc = [&](size_t bytes) { void* p = w + off; off += (bytes + 255) & ~(size_t)255; return p; };
    unsigned short* hb0 = (unsigned short*)alloc((size_t)N_NODES * HID * 2);
    unsigned short* hb1 = (unsigned short*)alloc((size_t)N_NODES * HID * 2);
    float* norm_src = (float*)alloc((size_t)N_NODES * 4);
    float* norm_dst = (float*)alloc((size_t)N_NODES * 4);
    int*   row_off  = (int*)  alloc((size_t)(N_NODES + 1) * 4);
    int*   esrc     = (int*)  alloc((size_t)N_EDGES * 4);
    int2*  ebuf     = (int2*) alloc((size_t)N_EDGES * 8);
    int*   sbuf     = (int*)  alloc((size_t)N_EDGES * 4);
    int*   cnt_d    = (int*)  alloc((size_t)NTOT * 4);
    int*   cnt_s    = (int*)  alloc((size_t)NTOT * 4);
    int*   offs_d   = (int*)  alloc((size_t)NTOT * 4);
    int*   offs_s   = (int*)  alloc((size_t)NTOT * 4);
    int*   bsums    = (int*)  alloc(1024 * 4);
    float* pooled   = (float*)alloc((size_t)N_GRAPHS * HID * 4);
    unsigned short* wtin  = (unsigned short*)alloc(128 * 96 * 2);
    unsigned short* wtg   = (unsigned short*)alloc(3 * 128 * 128 * 2);
    unsigned short* wtout = (unsigned short*)alloc(128 * 128 * 2);

    const int NB_SCAN = NTOT / 256;   // 782 exactly

    // ---- CSR build, no global atomics ----
    count_kernel<<<G1, 256, 0, stream>>>(src, dst, cnt_d, cnt_s);
    gscan1<<<NB_SCAN, 256, 0, stream>>>(cnt_d, offs_d, bsums, NTOT);
    gscan2<<<1, 1024, 0, stream>>>(bsums, NB_SCAN);
    gscan3<<<NB_SCAN, 256, 0, stream>>>(offs_d, bsums, NTOT);
    gscan1<<<NB_SCAN, 256, 0, stream>>>(cnt_s, offs_s, bsums, NTOT);
    gscan2<<<1, 1024, 0, stream>>>(bsums, NB_SCAN);
    gscan3<<<NB_SCAN, 256, 0, stream>>>(offs_s, bsums, NTOT);
    scatter_kernel<<<G1, 256, 0, stream>>>(src, dst, offs_d, offs_s, ebuf, sbuf);
    csr_kernel<<<NBUCK, 512, 0, stream>>>(ebuf, offs_d, row_off, esrc, norm_dst);
    degsrc_kernel<<<NBUCK, 512, 0, stream>>>(sbuf, offs_s, norm_src);

    wprep_kernel<<<(128 * 96 + 4 * 128 * 128 + 255) / 256, 256, 0, stream>>>(
        w_in, gw, w_out, wtin, wtg, wtout);

    const int NB_M = N_NODES / 64;   // 3125 exactly

    // h = silu(x @ w_in + b_in) * norm_src   -> bf16
    inproj_gemm<<<NB_M, 256, 0, stream>>>(x, wtin, b_in, norm_src, hb0);

    // conv1, conv2 (fused gather+GEMM), conv3+out-proj (double GEMM)
    fused_conv<true,  false><<<NB_M, 256, 0, stream>>>(
        hb0, esrc, row_off, norm_dst, wtg + 0 * HID * HID, gb + 0 * HID, norm_src,
        (const unsigned short*)nullptr, (const float*)nullptr, hb1);
    fused_conv<true,  false><<<NB_M, 256, 0, stream>>>(
        hb1, esrc, row_off, norm_dst, wtg + 1 * HID * HID, gb + 1 * HID, norm_src,
        (const unsigned short*)nullptr, (const float*)nullptr, hb0);
    fused_conv<false, true><<<NB_M, 256, 0, stream>>>(
        hb0, esrc, row_off, norm_dst, wtg + 2 * HID * HID, gb + 2 * HID, norm_src,
        wtout, b_out, hb1);

    // pooled = segment_sum(h, gid)
    pool_kernel<<<N_GRAPHS / 4, 256, 0, stream>>>(hb1, gid, pooled);

    // out = pooled @ w_ff + b_ff (fp32)
    gemm_kernel<HID, false><<<(N_GRAPHS + 31) / 32, 256, 0, stream>>>(pooled, w_ff, b_ff, out, N_GRAPHS);
}

// Round 10
// 587.279 us; speedup vs baseline: 6.2196x; 6.2196x over previous
//
#include <hip/hip_runtime.h>
#include <math.h>

#define N_NODES  200000
#define N_EDGES  1600000
#define N_GRAPHS 10000
#define IN_F     74
#define HID      128
#define DEPTH    3

#define NBUCK 391          // ceil(N_NODES / 512): bucket = id >> 9
#define G1    512          // blocks in count/scatter pass
#define CHUNK 3125         // N_EDGES / G1 (exact)
#define NTOT  (NBUCK * G1) // 200192 scan elements
#define ECAP  1024         // staged edges per conv block (mean 512, sd ~23)

typedef __attribute__((ext_vector_type(8))) short short8;
typedef __attribute__((ext_vector_type(8))) unsigned short ushort8v;
typedef __attribute__((ext_vector_type(4))) float floatx4;

__device__ __forceinline__ float silu_f(float x) {
    return x / (1.0f + __expf(-x));
}

__device__ __forceinline__ unsigned short f2bf(float f) {
    union { float f; unsigned int u; } v; v.f = f;
    unsigned int r = (v.u + 0x7fff + ((v.u >> 16) & 1)) >> 16;   // RNE
    return (unsigned short)r;
}

__device__ __forceinline__ float bf2f(unsigned short u) {
    union { unsigned int u; float f; } v; v.u = ((unsigned int)u) << 16;
    return v.f;
}

// accumulate a packed bf16 pair (one uint) into a float2
__device__ __forceinline__ void acc_pair(float2& a, unsigned int w) {
    union { unsigned int u; float f; } lo, hi;
    lo.u = w << 16;
    hi.u = w & 0xFFFF0000u;
    a.x += lo.f;
    a.y += hi.f;
}

// ================= atomic-free CSR build (radix partition by id>>9) =================

__global__ void count_kernel(const int* __restrict__ src, const int* __restrict__ dst,
                             int* __restrict__ cnt_d, int* __restrict__ cnt_s) {
    __shared__ int hd[NBUCK], hs[NBUCK];
    int t = threadIdx.x, b = blockIdx.x;
    for (int i = t; i < NBUCK; i += 256) { hd[i] = 0; hs[i] = 0; }
    __syncthreads();
    int e0 = b * CHUNK;
    for (int i = t; i < CHUNK; i += 256) {
        int e = e0 + i;
        atomicAdd(&hd[dst[e] >> 9], 1);
        atomicAdd(&hs[src[e] >> 9], 1);
    }
    __syncthreads();
    for (int i = t; i < NBUCK; i += 256) {
        cnt_d[i * G1 + b] = hd[i];
        cnt_s[i * G1 + b] = hs[i];
    }
}

__global__ void gscan1(const int* __restrict__ in, int* __restrict__ out,
                       int* __restrict__ bsums, int n) {
    __shared__ int a[256], b2[256];
    int t = threadIdx.x;
    int i = blockIdx.x * 256 + t;
    a[t] = (i < n) ? in[i] : 0;
    __syncthreads();
    int* s = a; int* d = b2;
    #pragma unroll
    for (int off = 1; off < 256; off <<= 1) {
        int v = s[t];
        if (t >= off) v += s[t - off];
        d[t] = v;
        __syncthreads();
        int* tmp = s; s = d; d = tmp;
    }
    if (i < n) out[i] = (t ? s[t - 1] : 0);
    if (t == 255) bsums[blockIdx.x] = s[255];
}

__global__ void gscan2(int* __restrict__ bsums, int nb) {
    __shared__ int a[1024], b[1024];
    int t = threadIdx.x;
    a[t] = (t < nb) ? bsums[t] : 0;
    __syncthreads();
    int* s = a; int* d = b;
    for (int off = 1; off < 1024; off <<= 1) {
        int v = s[t];
        if (t >= off) v += s[t - off];
        d[t] = v;
        __syncthreads();
        int* tmp = s; s = d; d = tmp;
    }
    if (t < nb) bsums[t] = s[t];
}

__global__ void gscan3(int* __restrict__ out, const int* __restrict__ bsums, int n) {
    int i = blockIdx.x * 256 + threadIdx.x;
    if (i < n && blockIdx.x > 0) out[i] += bsums[blockIdx.x - 1];
}

__global__ void scatter_kernel(const int* __restrict__ src, const int* __restrict__ dst,
                               const int* __restrict__ offs_d, const int* __restrict__ offs_s,
                               int2* __restrict__ ebuf, int* __restrict__ sbuf) {
    __shared__ int cd[NBUCK], cs[NBUCK];
    int t = threadIdx.x, b = blockIdx.x;
    for (int i = t; i < NBUCK; i += 256) {
        cd[i] = offs_d[i * G1 + b];
        cs[i] = offs_s[i * G1 + b];
    }
    __syncthreads();
    int e0 = b * CHUNK;
    for (int i = t; i < CHUNK; i += 256) {
        int e = e0 + i;
        int d = dst[e], s = src[e];
        int pd = atomicAdd(&cd[d >> 9], 1);
        int2 p; p.x = d; p.y = s;
        ebuf[pd] = p;
        int ps = atomicAdd(&cs[s >> 9], 1);
        sbuf[ps] = s;
    }
}

// esrc is PACKED: src (18 bits) | dst_local_to_64_block (6 bits) << 18
__global__ __launch_bounds__(512)
void csr_kernel(const int2* __restrict__ ebuf, const int* __restrict__ offs_d,
                int* __restrict__ row_off, int* __restrict__ esrc,
                float* __restrict__ norm_dst) {
    __shared__ int deg[512];
    __shared__ int sa[512], sb[512];
    int k = blockIdx.x, t = threadIdx.x;
    int base = k << 9;
    int estart = offs_d[k * G1];
    int eend = (k + 1 < NBUCK) ? offs_d[(k + 1) * G1] : N_EDGES;
    deg[t] = 0;
    __syncthreads();
    for (int e = estart + t; e < eend; e += 512)
        atomicAdd(&deg[ebuf[e].x - base], 1);
    __syncthreads();
    sa[t] = deg[t];
    __syncthreads();
    int* ps = sa; int* pd = sb;
    #pragma unroll
    for (int off = 1; off < 512; off <<= 1) {
        int v = ps[t];
        if (t >= off) v += ps[t - off];
        pd[t] = v;
        __syncthreads();
        int* tmp = ps; ps = pd; pd = tmp;
    }
    int excl = t ? ps[t - 1] : 0;
    int n = base + t;
    if (n <= N_NODES) row_off[n] = estart + excl;
    if (n < N_NODES)  norm_dst[n] = rsqrtf(fmaxf((float)deg[t], 1.0f));
    __syncthreads();
    pd[t] = estart + excl;
    __syncthreads();
    for (int e = estart + t; e < eend; e += 512) {
        int2 ed = ebuf[e];
        int pos = atomicAdd(&pd[ed.x - base], 1);
        esrc[pos] = ed.y | ((ed.x & 63) << 18);
    }
}

__global__ __launch_bounds__(512)
void degsrc_kernel(const int* __restrict__ sbuf, const int* __restrict__ offs_s,
                   float* __restrict__ norm_src) {
    __shared__ int deg[512];
    int k = blockIdx.x, t = threadIdx.x;
    int base = k << 9;
    int estart = offs_s[k * G1];
    int eend = (k + 1 < NBUCK) ? offs_s[(k + 1) * G1] : N_EDGES;
    deg[t] = 0;
    __syncthreads();
    for (int e = estart + t; e < eend; e += 512)
        atomicAdd(&deg[sbuf[e] - base], 1);
    __syncthreads();
    int n = base + t;
    if (n < N_NODES) norm_src[n] = rsqrtf(fmaxf((float)deg[t], 1.0f));
}

// ================= weight prep =================
__global__ void wprep_kernel(const float* __restrict__ w_in, const float* __restrict__ gw,
                             const float* __restrict__ w_out,
                             unsigned short* __restrict__ wtin,   // [128][96]
                             unsigned short* __restrict__ wtg,    // [3][128][128]
                             unsigned short* __restrict__ wtout)  // [128][128]
{
    int i = blockIdx.x * 256 + threadIdx.x;
    if (i < 128 * 96) {
        int n = i / 96, k = i - n * 96;
        wtin[i] = (k < IN_F) ? f2bf(w_in[k * 128 + n]) : (unsigned short)0;
    } else if (i < 128 * 96 + 3 * 128 * 128) {
        int j = i - 128 * 96;
        int layer = j / 16384, r = j - layer * 16384;
        int n = r >> 7, k = r & 127;
        wtg[j] = f2bf(gw[((size_t)layer * 128 + k) * 128 + n]);
    } else if (i < 128 * 96 + 3 * 128 * 128 + 128 * 128) {
        int j = i - (128 * 96 + 3 * 128 * 128);
        int n = j >> 7, k = j & 127;
        wtout[j] = f2bf(w_out[k * 128 + n]);
    }
}

// ================= fused conv: LDS-staged-idx gather -> MFMA -> silu [-> MFMA2 -> silu] =================
// Block: 256 threads, 64 dst nodes (N_NODES % 64 == 0).
// Gather: edge indices staged into LDS first (kills the idx->row dependent chain),
// then 16 lanes per node with REGISTER accumulation, 8-deep row loads in flight.
// MFMA tiles in fragment layout: A[(kchunk*64+m)*8+q], B[(kchunk*128+n)*8+q].
template<bool SCALE_NORM, bool SECOND>
__launch_bounds__(256)
__global__ void fused_conv(const unsigned short* __restrict__ h,
                           const int* __restrict__ esrc, const int* __restrict__ row_off,
                           const float* __restrict__ norm_dst,
                           const unsigned short* __restrict__ WT,   // [128][128]
                           const float* __restrict__ bias, const float* __restrict__ norm_src,
                           const unsigned short* __restrict__ WT2,  // [128][128] (SECOND)
                           const float* __restrict__ bias2,
                           unsigned short* __restrict__ out) {
    __shared__ unsigned short lds_af[64 * 128];     // 16 KB: A fragments / C repack
    __shared__ unsigned short lds_bf[16 * 128 * 8]; // 32 KB: B fragments
    __shared__ int lds_idx[ECAP];                   // 4 KB: staged edge indices
    __shared__ int lds_off[65];

    const int t = threadIdx.x;
    const int rowbase = blockIdx.x * 64;

    // ---- stage row offsets, B fragments, edge indices ----
    if (t < 65) lds_off[t] = row_off[rowbase + t];
    #pragma unroll
    for (int k = 0; k < 8; ++k) {
        int j = k * 256 + t;
        *(ushort8v*)&lds_bf[((j & 15) * 128 + (j >> 4)) * 8] =
            *(const ushort8v*)(WT + (j >> 4) * 128 + (j & 15) * 8);
    }
    const int beg  = row_off[rowbase];
    const int ecnt = row_off[rowbase + 64] - beg;
    if (ecnt <= ECAP)
        for (int o = t; o < ecnt; o += 256) lds_idx[o] = esrc[beg + o];
    __syncthreads();

    // ---- gather: 16 lanes per node, idx from LDS, register accumulation ----
    const int grp = t >> 4, c = t & 15;
    auto gather = [&](auto IDXF) {
        #pragma unroll
        for (int g = 0; g < 4; ++g) {
            int r = g * 16 + grp;
            int o = lds_off[r] - beg, oe = lds_off[r + 1] - beg;
            float2 a2[4];
            #pragma unroll
            for (int k = 0; k < 4; ++k) a2[k] = (float2){0.f, 0.f};
            for (; o + 7 < oe; o += 8) {
                int s[8];
                #pragma unroll
                for (int u = 0; u < 8; ++u) s[u] = IDXF(o + u) & 0x3FFFF;
                uint4 w[8];
                #pragma unroll
                for (int u = 0; u < 8; ++u)
                    w[u] = *(const uint4*)(h + (size_t)s[u] * HID + c * 8);
                #pragma unroll
                for (int u = 0; u < 8; ++u) {
                    acc_pair(a2[0], w[u].x);
                    acc_pair(a2[1], w[u].y);
                    acc_pair(a2[2], w[u].z);
                    acc_pair(a2[3], w[u].w);
                }
            }
            for (; o + 3 < oe; o += 4) {
                int s[4];
                #pragma unroll
                for (int u = 0; u < 4; ++u) s[u] = IDXF(o + u) & 0x3FFFF;
                uint4 w[4];
                #pragma unroll
                for (int u = 0; u < 4; ++u)
                    w[u] = *(const uint4*)(h + (size_t)s[u] * HID + c * 8);
                #pragma unroll
                for (int u = 0; u < 4; ++u) {
                    acc_pair(a2[0], w[u].x);
                    acc_pair(a2[1], w[u].y);
                    acc_pair(a2[2], w[u].z);
                    acc_pair(a2[3], w[u].w);
                }
            }
            for (; o < oe; ++o) {
                int s0 = IDXF(o) & 0x3FFFF;
                uint4 w0 = *(const uint4*)(h + (size_t)s0 * HID + c * 8);
                acc_pair(a2[0], w0.x);
                acc_pair(a2[1], w0.y);
                acc_pair(a2[2], w0.z);
                acc_pair(a2[3], w0.w);
            }
            float nd = norm_dst[rowbase + r];
            ushort8v ov;
            #pragma unroll
            for (int k = 0; k < 4; ++k) {
                ov[2 * k]     = f2bf(a2[k].x * nd);
                ov[2 * k + 1] = f2bf(a2[k].y * nd);
            }
            *(ushort8v*)&lds_af[(c * 64 + r) * 8] = ov;
        }
    };
    if (ecnt <= ECAP) gather([&](int o) { return lds_idx[o]; });
    else              gather([&](int o) { return esrc[beg + o]; });
    __syncthreads();

    const int lane = t & 63;
    const int w  = t >> 6;
    const int wr = w & 1;
    const int wc = w >> 1;
    const int l15 = lane & 15, quad = lane >> 4;

    floatx4 acc[4][2];
    #pragma unroll
    for (int tn = 0; tn < 4; ++tn)
        #pragma unroll
        for (int rt = 0; rt < 2; ++rt)
            acc[tn][rt] = (floatx4){0.f, 0.f, 0.f, 0.f};

    // ---- K-loop 1 (fragment reads) ----
    #pragma unroll
    for (int ks = 0; ks < 4; ++ks) {
        int kc = ks * 4 + quad;
        short8 bk[4];
        #pragma unroll
        for (int tn = 0; tn < 4; ++tn)
            bk[tn] = *(const short8*)&lds_bf[(kc * 128 + wc * 64 + tn * 16 + l15) * 8];
        short8 af[2];
        #pragma unroll
        for (int rt = 0; rt < 2; ++rt)
            af[rt] = *(const short8*)&lds_af[(kc * 64 + wr * 32 + rt * 16 + l15) * 8];
        #pragma unroll
        for (int tn = 0; tn < 4; ++tn)
            #pragma unroll
            for (int rt = 0; rt < 2; ++rt)
                acc[tn][rt] = __builtin_amdgcn_mfma_f32_16x16x32_bf16(
                    af[rt], bk[tn], acc[tn][rt], 0, 0, 0);
    }

    __syncthreads();   // everyone done reading lds_af / lds_bf

    if constexpr (SECOND) {
        // ---- epilogue 1 -> A2 fragments; B2 global -> LDS ----
        #pragma unroll
        for (int tn = 0; tn < 4; ++tn) {
            int col = wc * 64 + tn * 16 + l15;
            float b = bias[col];
            int c2 = col >> 3, q2 = col & 7;
            #pragma unroll
            for (int rt = 0; rt < 2; ++rt) {
                #pragma unroll
                for (int r = 0; r < 4; ++r) {
                    int row = wr * 32 + rt * 16 + quad * 4 + r;
                    float v = silu_f(acc[tn][rt][r] + b);
                    if (SCALE_NORM) v *= norm_src[rowbase + row];
                    lds_af[(c2 * 64 + row) * 8 + q2] = f2bf(v);
                }
            }
        }
        #pragma unroll
        for (int k = 0; k < 8; ++k) {
            int j = k * 256 + t;
            *(ushort8v*)&lds_bf[((j & 15) * 128 + (j >> 4)) * 8] =
                *(const ushort8v*)(WT2 + (j >> 4) * 128 + (j & 15) * 8);
        }
        #pragma unroll
        for (int tn = 0; tn < 4; ++tn)
            #pragma unroll
            for (int rt = 0; rt < 2; ++rt)
                acc[tn][rt] = (floatx4){0.f, 0.f, 0.f, 0.f};
        __syncthreads();

        // ---- K-loop 2 ----
        #pragma unroll
        for (int ks = 0; ks < 4; ++ks) {
            int kc = ks * 4 + quad;
            short8 bk[4];
            #pragma unroll
            for (int tn = 0; tn < 4; ++tn)
                bk[tn] = *(const short8*)&lds_bf[(kc * 128 + wc * 64 + tn * 16 + l15) * 8];
            short8 af[2];
            #pragma unroll
            for (int rt = 0; rt < 2; ++rt)
                af[rt] = *(const short8*)&lds_af[(kc * 64 + wr * 32 + rt * 16 + l15) * 8];
            #pragma unroll
            for (int tn = 0; tn < 4; ++tn)
                #pragma unroll
                for (int rt = 0; rt < 2; ++rt)
                    acc[tn][rt] = __builtin_amdgcn_mfma_f32_16x16x32_bf16(
                        af[rt], bk[tn], acc[tn][rt], 0, 0, 0);
        }
        __syncthreads();

        // ---- epilogue 2 -> row-major lds_af ----
        #pragma unroll
        for (int tn = 0; tn < 4; ++tn) {
            int col = wc * 64 + tn * 16 + l15;
            float b = bias2[col];
            #pragma unroll
            for (int rt = 0; rt < 2; ++rt) {
                #pragma unroll
                for (int r = 0; r < 4; ++r) {
                    int row = wr * 32 + rt * 16 + quad * 4 + r;
                    lds_af[row * 128 + col] = f2bf(silu_f(acc[tn][rt][r] + b));
                }
            }
        }
    } else {
        // ---- epilogue -> row-major lds_af ----
        #pragma unroll
        for (int tn = 0; tn < 4; ++tn) {
            int col = wc * 64 + tn * 16 + l15;
            float b = bias[col];
            #pragma unroll
            for (int rt = 0; rt < 2; ++rt) {
                #pragma unroll
                for (int r = 0; r < 4; ++r) {
                    int row = wr * 32 + rt * 16 + quad * 4 + r;
                    float v = silu_f(acc[tn][rt][r] + b);
                    if (SCALE_NORM) v *= norm_src[rowbase + row];
                    lds_af[row * 128 + col] = f2bf(v);
                }
            }
        }
    }

    __syncthreads();
    // ---- coalesced bf16 store ----
    #pragma unroll
    for (int j = 0; j < 4; ++j) {
        int e = j * 256 + t;
        int r = e >> 4;
        int cc = (e & 15) * 8;
        *(ushort8v*)(out + (size_t)(rowbase + r) * 128 + cc) = *(const ushort8v*)&lds_af[r * 128 + cc];
    }
}

// ================= input projection: fp32 x [N][74] @ wtin -> silu * norm_src -> bf16 =================
__launch_bounds__(256)
__global__ void inproj_gemm(const float* __restrict__ in, const unsigned short* __restrict__ WT,
                            const float* __restrict__ bias, const float* __restrict__ norm_src,
                            unsigned short* __restrict__ out) {
    constexpr int KP = 96, ASTR = 136, BSTR = 104;
    __shared__ unsigned short lds_a[64 * ASTR];
    __shared__ unsigned short lds_b[128 * BSTR];
    const int t = threadIdx.x;
    const int rowbase = blockIdx.x * 64;

    #pragma unroll
    for (int j = 0; j < 6; ++j) {
        int slot = j * 256 + t;
        int n = slot / 12, k = (slot - n * 12) * 8;
        *(ushort8v*)&lds_b[n * BSTR + k] = *(const ushort8v*)(WT + n * KP + k);
    }

    for (int i = t; i < 64 * 37; i += 256) {
        int r = i / 37, kk = (i - r * 37) * 2;
        float2 v = *(const float2*)(in + (size_t)(rowbase + r) * IN_F + kk);
        lds_a[r * ASTR + kk]     = f2bf(v.x);
        lds_a[r * ASTR + kk + 1] = f2bf(v.y);
    }
    for (int i = t; i < 64 * 22; i += 256) {
        int r = i / 22, kk = 74 + (i - r * 22);
        lds_a[r * ASTR + kk] = 0;
    }

    const int lane = t & 63;
    const int w  = t >> 6;
    const int wr = w & 1;
    const int wc = w >> 1;
    const int l15 = lane & 15, quad = lane >> 4;

    floatx4 acc[4][2];
    #pragma unroll
    for (int tn = 0; tn < 4; ++tn)
        #pragma unroll
        for (int rt = 0; rt < 2; ++rt)
            acc[tn][rt] = (floatx4){0.f, 0.f, 0.f, 0.f};

    __syncthreads();

    #pragma unroll
    for (int ks = 0; ks < 3; ++ks) {
        short8 bk[4];
        #pragma unroll
        for (int tn = 0; tn < 4; ++tn)
            bk[tn] = *(const short8*)&lds_b[(wc * 64 + tn * 16 + l15) * BSTR + ks * 32 + quad * 8];
        short8 af[2];
        #pragma unroll
        for (int rt = 0; rt < 2; ++rt)
            af[rt] = *(const short8*)&lds_a[(wr * 32 + rt * 16 + l15) * ASTR + ks * 32 + quad * 8];
        #pragma unroll
        for (int tn = 0; tn < 4; ++tn)
            #pragma unroll
            for (int rt = 0; rt < 2; ++rt)
                acc[tn][rt] = __builtin_amdgcn_mfma_f32_16x16x32_bf16(
                    af[rt], bk[tn], acc[tn][rt], 0, 0, 0);
    }

    __syncthreads();
    #pragma unroll
    for (int tn = 0; tn < 4; ++tn) {
        int col = wc * 64 + tn * 16 + l15;
        float b = bias[col];
        #pragma unroll
        for (int rt = 0; rt < 2; ++rt) {
            #pragma unroll
            for (int r = 0; r < 4; ++r) {
                int row = wr * 32 + rt * 16 + quad * 4 + r;
                float v = silu_f(acc[tn][rt][r] + b) * norm_src[rowbase + row];
                lds_a[row * ASTR + col] = f2bf(v);
            }
        }
    }
    __syncthreads();
    #pragma unroll
    for (int j = 0; j < 4; ++j) {
        int e = j * 256 + t;
        int r = e >> 4;
        int c = (e & 15) * 8;
        *(ushort8v*)(out + (size_t)(rowbase + r) * 128 + c) = *(const ushort8v*)&lds_a[r * ASTR + c];
    }
}

// ================= fp32 GEMM (small final matmul) =================
template<int K, bool DO_SILU>
__launch_bounds__(256)
__global__ void gemm_kernel(const float* __restrict__ in, const float* __restrict__ W,
                            const float* __restrict__ bias, float* __restrict__ out, int nrows) {
    __shared__ float wl[64 * HID];
    __shared__ float xl[32 * K];
    int t = threadIdx.x;
    int row0 = blockIdx.x * 32;

    for (int i = t; i < 32 * K; i += 256) {
        int r = i / K, k = i - r * K;
        int gr = row0 + r;
        xl[i] = (gr < nrows) ? in[(size_t)gr * K + k] : 0.0f;
    }

    int col = t & (HID - 1);
    int rg  = t >> 7;
    float acc[16];
    #pragma unroll
    for (int rr = 0; rr < 16; ++rr) acc[rr] = 0.0f;

    for (int c = 0; c < K; c += 64) {
        int kc = (K - c < 64) ? (K - c) : 64;
        __syncthreads();
        for (int i = t; i < kc * HID; i += 256) wl[i] = W[(size_t)c * HID + i];
        __syncthreads();
        for (int kk = 0; kk < kc; ++kk) {
            float w = wl[kk * HID + col];
            int k = c + kk;
            #pragma unroll
            for (int rr = 0; rr < 16; ++rr)
                acc[rr] += xl[(rg * 16 + rr) * K + k] * w;
        }
    }

    float b = bias[col];
    #pragma unroll
    for (int rr = 0; rr < 16; ++rr) {
        int r = row0 + rg * 16 + rr;
        if (r < nrows) {
            float v = acc[rr] + b;
            if (DO_SILU) v = silu_f(v);
            out[(size_t)r * HID + col] = v;
        }
    }
}

// ================= pooling: sorted graph_ids -> segmented sum =================
__device__ __forceinline__ int lower_bound_gid(const int* __restrict__ gid, int val) {
    int lo = 0, hi = N_NODES;
    while (lo < hi) {
        int mid = (lo + hi) >> 1;
        if (gid[mid] < val) lo = mid + 1; else hi = mid;
    }
    return lo;
}

__global__ void pool_kernel(const unsigned short* __restrict__ h, const int* __restrict__ gid,
                            float* __restrict__ pooled) {
    int g = blockIdx.x * 4 + (threadIdx.x >> 6);
    int lane = threadIdx.x & 63;
    int beg = lower_bound_gid(gid, g);
    int end = lower_bound_gid(gid, g + 1);
    float s0 = 0.0f, s1 = 0.0f;
    const unsigned int* hp = (const unsigned int*)h;
    for (int n = beg; n < end; ++n) {
        unsigned int u = hp[(size_t)n * 64 + lane];
        s0 += bf2f((unsigned short)(u & 0xffff));
        s1 += bf2f((unsigned short)(u >> 16));
    }
    float2 o; o.x = s0; o.y = s1;
    *(float2*)(pooled + (size_t)g * HID + lane * 2) = o;
}

extern "C" void kernel_launch(void* const* d_in, const int* in_sizes, int n_in,
                              void* d_out, int out_size, void* d_ws, size_t ws_size,
                              hipStream_t stream) {
    const float* x     = (const float*)d_in[0];
    const int*   src   = (const int*)  d_in[1];
    const int*   dst   = (const int*)  d_in[2];
    const int*   gid   = (const int*)  d_in[3];
    const float* w_in  = (const float*)d_in[4];
    const float* b_in  = (const float*)d_in[5];
    const float* gw    = (const float*)d_in[6];
    const float* gb    = (const float*)d_in[7];
    const float* w_out = (const float*)d_in[8];
    const float* b_out = (const float*)d_in[9];
    const float* w_ff  = (const float*)d_in[10];
    const float* b_ff  = (const float*)d_in[11];
    float* out = (float*)d_out;

    char* w = (char*)d_ws;
    size_t off = 0;
    auto alloc = [&](size_t bytes) { void* p = w + off; off += (bytes + 255) & ~(size_t)255; return p; };
    unsigned short* hb0 = (unsigned short*)alloc((size_t)N_NODES * HID * 2);
    unsigned short* hb1 = (unsigned short*)alloc((size_t)N_NODES * HID * 2);
    float* norm_src = (float*)alloc((size_t)N_NODES * 4);
    float* norm_dst = (float*)alloc((size_t)N_NODES * 4);
    int*   row_off  = (int*)  alloc((size_t)(N_NODES + 1) * 4);
    int*   esrc     = (int*)  alloc((size_t)N_EDGES * 4);
    int2*  ebuf     = (int2*) alloc((size_t)N_EDGES * 8);
    int*   sbuf     = (int*)  alloc((size_t)N_EDGES * 4);
    int*   cnt_d    = (int*)  alloc((size_t)NTOT * 4);
    int*   cnt_s    = (int*)  alloc((size_t)NTOT * 4);
    int*   offs_d   = (int*)  alloc((size_t)NTOT * 4);
    int*   offs_s   = (int*)  alloc((size_t)NTOT * 4);
    int*   bsums    = (int*)  alloc(1024 * 4);
    float* pooled   = (float*)alloc((size_t)N_GRAPHS * HID * 4);
    unsigned short* wtin  = (unsigned short*)alloc(128 * 96 * 2);
    unsigned short* wtg   = (unsigned short*)alloc(3 * 128 * 128 * 2);
    unsigned short* wtout = (unsigned short*)alloc(128 * 128 * 2);

    const int NB_SCAN = NTOT / 256;   // 782 exactly

    // ---- CSR build, no global atomics ----
    count_kernel<<<G1, 256, 0, stream>>>(src, dst, cnt_d, cnt_s);
    gscan1<<<NB_SCAN, 256, 0, stream>>>(cnt_d, offs_d, bsums, NTOT);
    gscan2<<<1, 1024, 0, stream>>>(bsums, NB_SCAN);
    gscan3<<<NB_SCAN, 256, 0, stream>>>(offs_d, bsums, NTOT);
    gscan1<<<NB_SCAN, 256, 0, stream>>>(cnt_s, offs_s, bsums, NTOT);
    gscan2<<<1, 1024, 0, stream>>>(bsums, NB_SCAN);
    gscan3<<<NB_SCAN, 256, 0, stream>>>(offs_s, bsums, NTOT);
    scatter_kernel<<<G1, 256, 0, stream>>>(src, dst, offs_d, offs_s, ebuf, sbuf);
    csr_kernel<<<NBUCK, 512, 0, stream>>>(ebuf, offs_d, row_off, esrc, norm_dst);
    degsrc_kernel<<<NBUCK, 512, 0, stream>>>(sbuf, offs_s, norm_src);

    wprep_kernel<<<(128 * 96 + 4 * 128 * 128 + 255) / 256, 256, 0, stream>>>(
        w_in, gw, w_out, wtin, wtg, wtout);

    const int NB_M = N_NODES / 64;   // 3125 exactly

    // h = silu(x @ w_in + b_in) * norm_src   -> bf16
    inproj_gemm<<<NB_M, 256, 0, stream>>>(x, wtin, b_in, norm_src, hb0);

    // conv1, conv2 (fused gather+GEMM), conv3+out-proj (double GEMM)
    fused_conv<true,  false><<<NB_M, 256, 0, stream>>>(
        hb0, esrc, row_off, norm_dst, wtg + 0 * HID * HID, gb + 0 * HID, norm_src,
        (const unsigned short*)nullptr, (const float*)nullptr, hb1);
    fused_conv<true,  false><<<NB_M, 256, 0, stream>>>(
        hb1, esrc, row_off, norm_dst, wtg + 1 * HID * HID, gb + 1 * HID, norm_src,
        (const unsigned short*)nullptr, (const float*)nullptr, hb0);
    fused_conv<false, true><<<NB_M, 256, 0, stream>>>(
        hb0, esrc, row_off, norm_dst, wtg + 2 * HID * HID, gb + 2 * HID, norm_src,
        wtout, b_out, hb1);

    // pooled = segment_sum(h, gid)
    pool_kernel<<<N_GRAPHS / 4, 256, 0, stream>>>(hb1, gid, pooled);

    // out = pooled @ w_ff + b_ff (fp32)
    gemm_kernel<HID, false><<<(N_GRAPHS + 31) / 32, 256, 0, stream>>>(pooled, w_ff, b_ff, out, N_GRAPHS);
}

// Round 11
// 575.601 us; speedup vs baseline: 6.3458x; 1.0203x over previous
//
#include <hip/hip_runtime.h>
#include <math.h>

#define N_NODES  200000
#define N_EDGES  1600000
#define N_GRAPHS 10000
#define IN_F     74
#define HID      128
#define DEPTH    3

#define NBUCK 391          // ceil(N_NODES / 512): bucket = id >> 9
#define G1    512          // blocks in count/scatter pass
#define CHUNK 3125         // N_EDGES / G1 (exact)
#define NTOT  (NBUCK * G1) // 200192 scan elements
#define ECAP  1024         // staged edges per conv block (mean 512, sd ~23)

typedef __attribute__((ext_vector_type(8))) short short8;
typedef __attribute__((ext_vector_type(8))) unsigned short ushort8v;
typedef __attribute__((ext_vector_type(4))) float floatx4;

__device__ __forceinline__ float silu_f(float x) {
    return x / (1.0f + __expf(-x));
}

__device__ __forceinline__ unsigned short f2bf(float f) {
    union { float f; unsigned int u; } v; v.f = f;
    unsigned int r = (v.u + 0x7fff + ((v.u >> 16) & 1)) >> 16;   // RNE
    return (unsigned short)r;
}

__device__ __forceinline__ float bf2f(unsigned short u) {
    union { unsigned int u; float f; } v; v.u = ((unsigned int)u) << 16;
    return v.f;
}

// accumulate a packed bf16 pair (one uint) into a float2
__device__ __forceinline__ void acc_pair(float2& a, unsigned int w) {
    union { unsigned int u; float f; } lo, hi;
    lo.u = w << 16;
    hi.u = w & 0xFFFF0000u;
    a.x += lo.f;
    a.y += hi.f;
}

// ================= atomic-free CSR build (radix partition by id>>9) =================

__global__ void count_kernel(const int* __restrict__ src, const int* __restrict__ dst,
                             int* __restrict__ cnt_d, int* __restrict__ cnt_s) {
    __shared__ int hd[NBUCK], hs[NBUCK];
    int t = threadIdx.x, b = blockIdx.x;
    for (int i = t; i < NBUCK; i += 256) { hd[i] = 0; hs[i] = 0; }
    __syncthreads();
    int e0 = b * CHUNK;
    for (int i = t; i < CHUNK; i += 256) {
        int e = e0 + i;
        atomicAdd(&hd[dst[e] >> 9], 1);
        atomicAdd(&hs[src[e] >> 9], 1);
    }
    __syncthreads();
    for (int i = t; i < NBUCK; i += 256) {
        cnt_d[i * G1 + b] = hd[i];
        cnt_s[i * G1 + b] = hs[i];
    }
}

__global__ void gscan1(const int* __restrict__ in, int* __restrict__ out,
                       int* __restrict__ bsums, int n) {
    __shared__ int a[256], b2[256];
    int t = threadIdx.x;
    int i = blockIdx.x * 256 + t;
    a[t] = (i < n) ? in[i] : 0;
    __syncthreads();
    int* s = a; int* d = b2;
    #pragma unroll
    for (int off = 1; off < 256; off <<= 1) {
        int v = s[t];
        if (t >= off) v += s[t - off];
        d[t] = v;
        __syncthreads();
        int* tmp = s; s = d; d = tmp;
    }
    if (i < n) out[i] = (t ? s[t - 1] : 0);
    if (t == 255) bsums[blockIdx.x] = s[255];
}

__global__ void gscan2(int* __restrict__ bsums, int nb) {
    __shared__ int a[1024], b[1024];
    int t = threadIdx.x;
    a[t] = (t < nb) ? bsums[t] : 0;
    __syncthreads();
    int* s = a; int* d = b;
    for (int off = 1; off < 1024; off <<= 1) {
        int v = s[t];
        if (t >= off) v += s[t - off];
        d[t] = v;
        __syncthreads();
        int* tmp = s; s = d; d = tmp;
    }
    if (t < nb) bsums[t] = s[t];
}

__global__ void gscan3(int* __restrict__ out, const int* __restrict__ bsums, int n) {
    int i = blockIdx.x * 256 + threadIdx.x;
    if (i < n && blockIdx.x > 0) out[i] += bsums[blockIdx.x - 1];
}

__global__ void scatter_kernel(const int* __restrict__ src, const int* __restrict__ dst,
                               const int* __restrict__ offs_d, const int* __restrict__ offs_s,
                               int2* __restrict__ ebuf, int* __restrict__ sbuf) {
    __shared__ int cd[NBUCK], cs[NBUCK];
    int t = threadIdx.x, b = blockIdx.x;
    for (int i = t; i < NBUCK; i += 256) {
        cd[i] = offs_d[i * G1 + b];
        cs[i] = offs_s[i * G1 + b];
    }
    __syncthreads();
    int e0 = b * CHUNK;
    for (int i = t; i < CHUNK; i += 256) {
        int e = e0 + i;
        int d = dst[e], s = src[e];
        int pd = atomicAdd(&cd[d >> 9], 1);
        int2 p; p.x = d; p.y = s;
        ebuf[pd] = p;
        int ps = atomicAdd(&cs[s >> 9], 1);
        sbuf[ps] = s;
    }
}

// esrc is PACKED: src (18 bits) | dst_local_to_64_block (6 bits) << 18
__global__ __launch_bounds__(512)
void csr_kernel(const int2* __restrict__ ebuf, const int* __restrict__ offs_d,
                int* __restrict__ row_off, int* __restrict__ esrc,
                float* __restrict__ norm_dst) {
    __shared__ int deg[512];
    __shared__ int sa[512], sb[512];
    int k = blockIdx.x, t = threadIdx.x;
    int base = k << 9;
    int estart = offs_d[k * G1];
    int eend = (k + 1 < NBUCK) ? offs_d[(k + 1) * G1] : N_EDGES;
    deg[t] = 0;
    __syncthreads();
    for (int e = estart + t; e < eend; e += 512)
        atomicAdd(&deg[ebuf[e].x - base], 1);
    __syncthreads();
    sa[t] = deg[t];
    __syncthreads();
    int* ps = sa; int* pd = sb;
    #pragma unroll
    for (int off = 1; off < 512; off <<= 1) {
        int v = ps[t];
        if (t >= off) v += ps[t - off];
        pd[t] = v;
        __syncthreads();
        int* tmp = ps; ps = pd; pd = tmp;
    }
    int excl = t ? ps[t - 1] : 0;
    int n = base + t;
    if (n <= N_NODES) row_off[n] = estart + excl;
    if (n < N_NODES)  norm_dst[n] = rsqrtf(fmaxf((float)deg[t], 1.0f));
    __syncthreads();
    pd[t] = estart + excl;
    __syncthreads();
    for (int e = estart + t; e < eend; e += 512) {
        int2 ed = ebuf[e];
        int pos = atomicAdd(&pd[ed.x - base], 1);
        esrc[pos] = ed.y | ((ed.x & 63) << 18);
    }
}

__global__ __launch_bounds__(512)
void degsrc_kernel(const int* __restrict__ sbuf, const int* __restrict__ offs_s,
                   float* __restrict__ norm_src) {
    __shared__ int deg[512];
    int k = blockIdx.x, t = threadIdx.x;
    int base = k << 9;
    int estart = offs_s[k * G1];
    int eend = (k + 1 < NBUCK) ? offs_s[(k + 1) * G1] : N_EDGES;
    deg[t] = 0;
    __syncthreads();
    for (int e = estart + t; e < eend; e += 512)
        atomicAdd(&deg[sbuf[e] - base], 1);
    __syncthreads();
    int n = base + t;
    if (n < N_NODES) norm_src[n] = rsqrtf(fmaxf((float)deg[t], 1.0f));
}

// ================= weight prep =================
__global__ void wprep_kernel(const float* __restrict__ w_in, const float* __restrict__ gw,
                             const float* __restrict__ w_out,
                             unsigned short* __restrict__ wtin,   // [128][96]
                             unsigned short* __restrict__ wtg,    // [3][128][128]
                             unsigned short* __restrict__ wtout)  // [128][128]
{
    int i = blockIdx.x * 256 + threadIdx.x;
    if (i < 128 * 96) {
        int n = i / 96, k = i - n * 96;
        wtin[i] = (k < IN_F) ? f2bf(w_in[k * 128 + n]) : (unsigned short)0;
    } else if (i < 128 * 96 + 3 * 128 * 128) {
        int j = i - 128 * 96;
        int layer = j / 16384, r = j - layer * 16384;
        int n = r >> 7, k = r & 127;
        wtg[j] = f2bf(gw[((size_t)layer * 128 + k) * 128 + n]);
    } else if (i < 128 * 96 + 3 * 128 * 128 + 128 * 128) {
        int j = i - (128 * 96 + 3 * 128 * 128);
        int n = j >> 7, k = j & 127;
        wtout[j] = f2bf(w_out[k * 128 + n]);
    }
}

// ================= fused conv: LDS-staged-idx gather -> MFMA -> silu [-> MFMA2 -> silu] =================
// Block: 256 threads, 64 dst nodes (N_NODES % 64 == 0).
// Fragment layouts XOR-swizzled so STORES are bank-conflict-free (round-10's 16-way
// store conflicts: word addr had chunk*256 ≡ 0 mod 32 -> all 16 lanes on 4 banks):
//   A frag (chunk c, row r):  lds_af[(c*64 + (r ^ (c&7))) * 8]
//   B frag (chunk kc, col n): lds_bf[(kc*128 + (n ^ (kc&7))) * 8]
// Reads XOR with the same key: permutes within an aligned 16-block -> still conflict-free.
template<bool SCALE_NORM, bool SECOND>
__launch_bounds__(256)
__global__ void fused_conv(const unsigned short* __restrict__ h,
                           const int* __restrict__ esrc, const int* __restrict__ row_off,
                           const float* __restrict__ norm_dst,
                           const unsigned short* __restrict__ WT,   // [128][128]
                           const float* __restrict__ bias, const float* __restrict__ norm_src,
                           const unsigned short* __restrict__ WT2,  // [128][128] (SECOND)
                           const float* __restrict__ bias2,
                           unsigned short* __restrict__ out) {
    __shared__ unsigned short lds_af[64 * 128];     // 16 KB: A fragments / C repack
    __shared__ unsigned short lds_bf[16 * 128 * 8]; // 32 KB: B fragments
    __shared__ int lds_idx[ECAP];                   // 4 KB: staged edge indices
    __shared__ int lds_off[65];

    const int t = threadIdx.x;
    const int rowbase = blockIdx.x * 64;

    // ---- stage row offsets, B fragments (swizzled), edge indices ----
    if (t < 65) lds_off[t] = row_off[rowbase + t];
    #pragma unroll
    for (int k = 0; k < 8; ++k) {
        int j = k * 256 + t;
        int kc = j & 15, n = j >> 4;
        *(ushort8v*)&lds_bf[(kc * 128 + (n ^ (kc & 7))) * 8] =
            *(const ushort8v*)(WT + n * 128 + kc * 8);
    }
    const int beg  = row_off[rowbase];
    const int ecnt = row_off[rowbase + 64] - beg;
    if (ecnt <= ECAP)
        for (int o = t; o < ecnt; o += 256) lds_idx[o] = esrc[beg + o];
    __syncthreads();

    // ---- gather: 16 lanes per node, idx from LDS, register accumulation ----
    const int grp = t >> 4, c = t & 15;
    auto gather = [&](auto IDXF) {
        #pragma unroll
        for (int g = 0; g < 4; ++g) {
            int r = g * 16 + grp;
            int o = lds_off[r] - beg, oe = lds_off[r + 1] - beg;
            float2 a2[4];
            #pragma unroll
            for (int k = 0; k < 4; ++k) a2[k] = (float2){0.f, 0.f};
            for (; o + 7 < oe; o += 8) {
                int s[8];
                #pragma unroll
                for (int u = 0; u < 8; ++u) s[u] = IDXF(o + u) & 0x3FFFF;
                uint4 w[8];
                #pragma unroll
                for (int u = 0; u < 8; ++u)
                    w[u] = *(const uint4*)(h + (size_t)s[u] * HID + c * 8);
                #pragma unroll
                for (int u = 0; u < 8; ++u) {
                    acc_pair(a2[0], w[u].x);
                    acc_pair(a2[1], w[u].y);
                    acc_pair(a2[2], w[u].z);
                    acc_pair(a2[3], w[u].w);
                }
            }
            for (; o + 3 < oe; o += 4) {
                int s[4];
                #pragma unroll
                for (int u = 0; u < 4; ++u) s[u] = IDXF(o + u) & 0x3FFFF;
                uint4 w[4];
                #pragma unroll
                for (int u = 0; u < 4; ++u)
                    w[u] = *(const uint4*)(h + (size_t)s[u] * HID + c * 8);
                #pragma unroll
                for (int u = 0; u < 4; ++u) {
                    acc_pair(a2[0], w[u].x);
                    acc_pair(a2[1], w[u].y);
                    acc_pair(a2[2], w[u].z);
                    acc_pair(a2[3], w[u].w);
                }
            }
            for (; o < oe; ++o) {
                int s0 = IDXF(o) & 0x3FFFF;
                uint4 w0 = *(const uint4*)(h + (size_t)s0 * HID + c * 8);
                acc_pair(a2[0], w0.x);
                acc_pair(a2[1], w0.y);
                acc_pair(a2[2], w0.z);
                acc_pair(a2[3], w0.w);
            }
            float nd = norm_dst[rowbase + r];
            ushort8v ov;
            #pragma unroll
            for (int k = 0; k < 4; ++k) {
                ov[2 * k]     = f2bf(a2[k].x * nd);
                ov[2 * k + 1] = f2bf(a2[k].y * nd);
            }
            *(ushort8v*)&lds_af[(c * 64 + (r ^ (c & 7))) * 8] = ov;
        }
    };
    if (ecnt <= ECAP) gather([&](int o) { return lds_idx[o]; });
    else              gather([&](int o) { return esrc[beg + o]; });
    __syncthreads();

    const int lane = t & 63;
    const int w  = t >> 6;
    const int wr = w & 1;
    const int wc = w >> 1;
    const int l15 = lane & 15, quad = lane >> 4;

    floatx4 acc[4][2];
    #pragma unroll
    for (int tn = 0; tn < 4; ++tn)
        #pragma unroll
        for (int rt = 0; rt < 2; ++rt)
            acc[tn][rt] = (floatx4){0.f, 0.f, 0.f, 0.f};

    // ---- K-loop 1 (swizzled fragment reads) ----
    #pragma unroll
    for (int ks = 0; ks < 4; ++ks) {
        int kc = ks * 4 + quad;
        int x = kc & 7;
        short8 bk[4];
        #pragma unroll
        for (int tn = 0; tn < 4; ++tn)
            bk[tn] = *(const short8*)&lds_bf[(kc * 128 + ((wc * 64 + tn * 16 + l15) ^ x)) * 8];
        short8 af[2];
        #pragma unroll
        for (int rt = 0; rt < 2; ++rt)
            af[rt] = *(const short8*)&lds_af[(kc * 64 + ((wr * 32 + rt * 16 + l15) ^ x)) * 8];
        #pragma unroll
        for (int tn = 0; tn < 4; ++tn)
            #pragma unroll
            for (int rt = 0; rt < 2; ++rt)
                acc[tn][rt] = __builtin_amdgcn_mfma_f32_16x16x32_bf16(
                    af[rt], bk[tn], acc[tn][rt], 0, 0, 0);
    }

    __syncthreads();   // everyone done reading lds_af / lds_bf

    if constexpr (SECOND) {
        // ---- epilogue 1 -> A2 fragments (swizzled); B2 global -> LDS (swizzled) ----
        #pragma unroll
        for (int tn = 0; tn < 4; ++tn) {
            int col = wc * 64 + tn * 16 + l15;
            float b = bias[col];
            int c2 = col >> 3, q2 = col & 7;
            #pragma unroll
            for (int rt = 0; rt < 2; ++rt) {
                #pragma unroll
                for (int r = 0; r < 4; ++r) {
                    int row = wr * 32 + rt * 16 + quad * 4 + r;
                    float v = silu_f(acc[tn][rt][r] + b);
                    if (SCALE_NORM) v *= norm_src[rowbase + row];
                    lds_af[(c2 * 64 + (row ^ (c2 & 7))) * 8 + q2] = f2bf(v);
                }
            }
        }
        #pragma unroll
        for (int k = 0; k < 8; ++k) {
            int j = k * 256 + t;
            int kc = j & 15, n = j >> 4;
            *(ushort8v*)&lds_bf[(kc * 128 + (n ^ (kc & 7))) * 8] =
                *(const ushort8v*)(WT2 + n * 128 + kc * 8);
        }
        #pragma unroll
        for (int tn = 0; tn < 4; ++tn)
            #pragma unroll
            for (int rt = 0; rt < 2; ++rt)
                acc[tn][rt] = (floatx4){0.f, 0.f, 0.f, 0.f};
        __syncthreads();

        // ---- K-loop 2 ----
        #pragma unroll
        for (int ks = 0; ks < 4; ++ks) {
            int kc = ks * 4 + quad;
            int x = kc & 7;
            short8 bk[4];
            #pragma unroll
            for (int tn = 0; tn < 4; ++tn)
                bk[tn] = *(const short8*)&lds_bf[(kc * 128 + ((wc * 64 + tn * 16 + l15) ^ x)) * 8];
            short8 af[2];
            #pragma unroll
            for (int rt = 0; rt < 2; ++rt)
                af[rt] = *(const short8*)&lds_af[(kc * 64 + ((wr * 32 + rt * 16 + l15) ^ x)) * 8];
            #pragma unroll
            for (int tn = 0; tn < 4; ++tn)
                #pragma unroll
                for (int rt = 0; rt < 2; ++rt)
                    acc[tn][rt] = __builtin_amdgcn_mfma_f32_16x16x32_bf16(
                        af[rt], bk[tn], acc[tn][rt], 0, 0, 0);
        }
        __syncthreads();

        // ---- epilogue 2 -> row-major lds_af ----
        #pragma unroll
        for (int tn = 0; tn < 4; ++tn) {
            int col = wc * 64 + tn * 16 + l15;
            float b = bias2[col];
            #pragma unroll
            for (int rt = 0; rt < 2; ++rt) {
                #pragma unroll
                for (int r = 0; r < 4; ++r) {
                    int row = wr * 32 + rt * 16 + quad * 4 + r;
                    lds_af[row * 128 + col] = f2bf(silu_f(acc[tn][rt][r] + b));
                }
            }
        }
    } else {
        // ---- epilogue -> row-major lds_af ----
        #pragma unroll
        for (int tn = 0; tn < 4; ++tn) {
            int col = wc * 64 + tn * 16 + l15;
            float b = bias[col];
            #pragma unroll
            for (int rt = 0; rt < 2; ++rt) {
                #pragma unroll
                for (int r = 0; r < 4; ++r) {
                    int row = wr * 32 + rt * 16 + quad * 4 + r;
                    float v = silu_f(acc[tn][rt][r] + b);
                    if (SCALE_NORM) v *= norm_src[rowbase + row];
                    lds_af[row * 128 + col] = f2bf(v);
                }
            }
        }
    }

    __syncthreads();
    // ---- coalesced bf16 store ----
    #pragma unroll
    for (int j = 0; j < 4; ++j) {
        int e = j * 256 + t;
        int r = e >> 4;
        int cc = (e & 15) * 8;
        *(ushort8v*)(out + (size_t)(rowbase + r) * 128 + cc) = *(const ushort8v*)&lds_af[r * 128 + cc];
    }
}

// ================= input projection: fp32 x [N][74] @ wtin -> silu * norm_src -> bf16 =================
__launch_bounds__(256)
__global__ void inproj_gemm(const float* __restrict__ in, const unsigned short* __restrict__ WT,
                            const float* __restrict__ bias, const float* __restrict__ norm_src,
                            unsigned short* __restrict__ out) {
    constexpr int KP = 96, ASTR = 136, BSTR = 104;
    __shared__ unsigned short lds_a[64 * ASTR];
    __shared__ unsigned short lds_b[128 * BSTR];
    const int t = threadIdx.x;
    const int rowbase = blockIdx.x * 64;

    #pragma unroll
    for (int j = 0; j < 6; ++j) {
        int slot = j * 256 + t;
        int n = slot / 12, k = (slot - n * 12) * 8;
        *(ushort8v*)&lds_b[n * BSTR + k] = *(const ushort8v*)(WT + n * KP + k);
    }

    for (int i = t; i < 64 * 37; i += 256) {
        int r = i / 37, kk = (i - r * 37) * 2;
        float2 v = *(const float2*)(in + (size_t)(rowbase + r) * IN_F + kk);
        lds_a[r * ASTR + kk]     = f2bf(v.x);
        lds_a[r * ASTR + kk + 1] = f2bf(v.y);
    }
    for (int i = t; i < 64 * 22; i += 256) {
        int r = i / 22, kk = 74 + (i - r * 22);
        lds_a[r * ASTR + kk] = 0;
    }

    const int lane = t & 63;
    const int w  = t >> 6;
    const int wr = w & 1;
    const int wc = w >> 1;
    const int l15 = lane & 15, quad = lane >> 4;

    floatx4 acc[4][2];
    #pragma unroll
    for (int tn = 0; tn < 4; ++tn)
        #pragma unroll
        for (int rt = 0; rt < 2; ++rt)
            acc[tn][rt] = (floatx4){0.f, 0.f, 0.f, 0.f};

    __syncthreads();

    #pragma unroll
    for (int ks = 0; ks < 3; ++ks) {
        short8 bk[4];
        #pragma unroll
        for (int tn = 0; tn < 4; ++tn)
            bk[tn] = *(const short8*)&lds_b[(wc * 64 + tn * 16 + l15) * BSTR + ks * 32 + quad * 8];
        short8 af[2];
        #pragma unroll
        for (int rt = 0; rt < 2; ++rt)
            af[rt] = *(const short8*)&lds_a[(wr * 32 + rt * 16 + l15) * ASTR + ks * 32 + quad * 8];
        #pragma unroll
        for (int tn = 0; tn < 4; ++tn)
            #pragma unroll
            for (int rt = 0; rt < 2; ++rt)
                acc[tn][rt] = __builtin_amdgcn_mfma_f32_16x16x32_bf16(
                    af[rt], bk[tn], acc[tn][rt], 0, 0, 0);
    }

    __syncthreads();
    #pragma unroll
    for (int tn = 0; tn < 4; ++tn) {
        int col = wc * 64 + tn * 16 + l15;
        float b = bias[col];
        #pragma unroll
        for (int rt = 0; rt < 2; ++rt) {
            #pragma unroll
            for (int r = 0; r < 4; ++r) {
                int row = wr * 32 + rt * 16 + quad * 4 + r;
                float v = silu_f(acc[tn][rt][r] + b) * norm_src[rowbase + row];
                lds_a[row * ASTR + col] = f2bf(v);
            }
        }
    }
    __syncthreads();
    #pragma unroll
    for (int j = 0; j < 4; ++j) {
        int e = j * 256 + t;
        int r = e >> 4;
        int c = (e & 15) * 8;
        *(ushort8v*)(out + (size_t)(rowbase + r) * 128 + c) = *(const ushort8v*)&lds_a[r * ASTR + c];
    }
}

// ================= fp32 GEMM (small final matmul) =================
template<int K, bool DO_SILU>
__launch_bounds__(256)
__global__ void gemm_kernel(const float* __restrict__ in, const float* __restrict__ W,
                            const float* __restrict__ bias, float* __restrict__ out, int nrows) {
    __shared__ float wl[64 * HID];
    __shared__ float xl[32 * K];
    int t = threadIdx.x;
    int row0 = blockIdx.x * 32;

    for (int i = t; i < 32 * K; i += 256) {
        int r = i / K, k = i - r * K;
        int gr = row0 + r;
        xl[i] = (gr < nrows) ? in[(size_t)gr * K + k] : 0.0f;
    }

    int col = t & (HID - 1);
    int rg  = t >> 7;
    float acc[16];
    #pragma unroll
    for (int rr = 0; rr < 16; ++rr) acc[rr] = 0.0f;

    for (int c = 0; c < K; c += 64) {
        int kc = (K - c < 64) ? (K - c) : 64;
        __syncthreads();
        for (int i = t; i < kc * HID; i += 256) wl[i] = W[(size_t)c * HID + i];
        __syncthreads();
        for (int kk = 0; kk < kc; ++kk) {
            float w = wl[kk * HID + col];
            int k = c + kk;
            #pragma unroll
            for (int rr = 0; rr < 16; ++rr)
                acc[rr] += xl[(rg * 16 + rr) * K + k] * w;
        }
    }

    float b = bias[col];
    #pragma unroll
    for (int rr = 0; rr < 16; ++rr) {
        int r = row0 + rg * 16 + rr;
        if (r < nrows) {
            float v = acc[rr] + b;
            if (DO_SILU) v = silu_f(v);
            out[(size_t)r * HID + col] = v;
        }
    }
}

// ================= pooling: sorted graph_ids -> segmented sum =================
__device__ __forceinline__ int lower_bound_gid(const int* __restrict__ gid, int val) {
    int lo = 0, hi = N_NODES;
    while (lo < hi) {
        int mid = (lo + hi) >> 1;
        if (gid[mid] < val) lo = mid + 1; else hi = mid;
    }
    return lo;
}

__global__ void pool_kernel(const unsigned short* __restrict__ h, const int* __restrict__ gid,
                            float* __restrict__ pooled) {
    int g = blockIdx.x * 4 + (threadIdx.x >> 6);
    int lane = threadIdx.x & 63;
    int beg = lower_bound_gid(gid, g);
    int end = lower_bound_gid(gid, g + 1);
    float s0 = 0.0f, s1 = 0.0f;
    const unsigned int* hp = (const unsigned int*)h;
    for (int n = beg; n < end; ++n) {
        unsigned int u = hp[(size_t)n * 64 + lane];
        s0 += bf2f((unsigned short)(u & 0xffff));
        s1 += bf2f((unsigned short)(u >> 16));
    }
    float2 o; o.x = s0; o.y = s1;
    *(float2*)(pooled + (size_t)g * HID + lane * 2) = o;
}

extern "C" void kernel_launch(void* const* d_in, const int* in_sizes, int n_in,
                              void* d_out, int out_size, void* d_ws, size_t ws_size,
                              hipStream_t stream) {
    const float* x     = (const float*)d_in[0];
    const int*   src   = (const int*)  d_in[1];
    const int*   dst   = (const int*)  d_in[2];
    const int*   gid   = (const int*)  d_in[3];
    const float* w_in  = (const float*)d_in[4];
    const float* b_in  = (const float*)d_in[5];
    const float* gw    = (const float*)d_in[6];
    const float* gb    = (const float*)d_in[7];
    const float* w_out = (const float*)d_in[8];
    const float* b_out = (const float*)d_in[9];
    const float* w_ff  = (const float*)d_in[10];
    const float* b_ff  = (const float*)d_in[11];
    float* out = (float*)d_out;

    char* w = (char*)d_ws;
    size_t off = 0;
    auto alloc = [&](size_t bytes) { void* p = w + off; off += (bytes + 255) & ~(size_t)255; return p; };
    unsigned short* hb0 = (unsigned short*)alloc((size_t)N_NODES * HID * 2);
    unsigned short* hb1 = (unsigned short*)alloc((size_t)N_NODES * HID * 2);
    float* norm_src = (float*)alloc((size_t)N_NODES * 4);
    float* norm_dst = (float*)alloc((size_t)N_NODES * 4);
    int*   row_off  = (int*)  alloc((size_t)(N_NODES + 1) * 4);
    int*   esrc     = (int*)  alloc((size_t)N_EDGES * 4);
    int2*  ebuf     = (int2*) alloc((size_t)N_EDGES * 8);
    int*   sbuf     = (int*)  alloc((size_t)N_EDGES * 4);
    int*   cnt_d    = (int*)  alloc((size_t)NTOT * 4);
    int*   cnt_s    = (int*)  alloc((size_t)NTOT * 4);
    int*   offs_d   = (int*)  alloc((size_t)NTOT * 4);
    int*   offs_s   = (int*)  alloc((size_t)NTOT * 4);
    int*   bsums    = (int*)  alloc(1024 * 4);
    float* pooled   = (float*)alloc((size_t)N_GRAPHS * HID * 4);
    unsigned short* wtin  = (unsigned short*)alloc(128 * 96 * 2);
    unsigned short* wtg   = (unsigned short*)alloc(3 * 128 * 128 * 2);
    unsigned short* wtout = (unsigned short*)alloc(128 * 128 * 2);

    const int NB_SCAN = NTOT / 256;   // 782 exactly

    // ---- CSR build, no global atomics ----
    count_kernel<<<G1, 256, 0, stream>>>(src, dst, cnt_d, cnt_s);
    gscan1<<<NB_SCAN, 256, 0, stream>>>(cnt_d, offs_d, bsums, NTOT);
    gscan2<<<1, 1024, 0, stream>>>(bsums, NB_SCAN);
    gscan3<<<NB_SCAN, 256, 0, stream>>>(offs_d, bsums, NTOT);
    gscan1<<<NB_SCAN, 256, 0, stream>>>(cnt_s, offs_s, bsums, NTOT);
    gscan2<<<1, 1024, 0, stream>>>(bsums, NB_SCAN);
    gscan3<<<NB_SCAN, 256, 0, stream>>>(offs_s, bsums, NTOT);
    scatter_kernel<<<G1, 256, 0, stream>>>(src, dst, offs_d, offs_s, ebuf, sbuf);
    csr_kernel<<<NBUCK, 512, 0, stream>>>(ebuf, offs_d, row_off, esrc, norm_dst);
    degsrc_kernel<<<NBUCK, 512, 0, stream>>>(sbuf, offs_s, norm_src);

    wprep_kernel<<<(128 * 96 + 4 * 128 * 128 + 255) / 256, 256, 0, stream>>>(
        w_in, gw, w_out, wtin, wtg, wtout);

    const int NB_M = N_NODES / 64;   // 3125 exactly

    // h = silu(x @ w_in + b_in) * norm_src   -> bf16
    inproj_gemm<<<NB_M, 256, 0, stream>>>(x, wtin, b_in, norm_src, hb0);

    // conv1, conv2 (fused gather+GEMM), conv3+out-proj (double GEMM)
    fused_conv<true,  false><<<NB_M, 256, 0, stream>>>(
        hb0, esrc, row_off, norm_dst, wtg + 0 * HID * HID, gb + 0 * HID, norm_src,
        (const unsigned short*)nullptr, (const float*)nullptr, hb1);
    fused_conv<true,  false><<<NB_M, 256, 0, stream>>>(
        hb1, esrc, row_off, norm_dst, wtg + 1 * HID * HID, gb + 1 * HID, norm_src,
        (const unsigned short*)nullptr, (const float*)nullptr, hb0);
    fused_conv<false, true><<<NB_M, 256, 0, stream>>>(
        hb0, esrc, row_off, norm_dst, wtg + 2 * HID * HID, gb + 2 * HID, norm_src,
        wtout, b_out, hb1);

    // pooled = segment_sum(h, gid)
    pool_kernel<<<N_GRAPHS / 4, 256, 0, stream>>>(hb1, gid, pooled);

    // out = pooled @ w_ff + b_ff (fp32)
    gemm_kernel<HID, false><<<(N_GRAPHS + 31) / 32, 256, 0, stream>>>(pooled, w_ff, b_ff, out, N_GRAPHS);
}